// Round 7
// baseline (148.176 us; speedup 1.0000x reference)
//
#include <hip/hip_runtime.h>
#include <math.h>

// ---------------------------------------------------------------------------
// Single fused kernel, 64-row x 1024-col tiles (512 blocks = 2/CU).
//
// Phase 1 — every block redundantly recomputes its batch's joint point
// moments in f64 (input 32 KB/batch, L2-broadcast). Cost is per-block-fixed
// (~2300 issue-cycles/wave), so chip-wide cost scales with block count:
// 2048 blocks (R6) ~8 us -> 512 blocks ~2 us. Closed-form mean/std(ddof=1):
//   sum_d  = 2N(S2x+S2y) - 2(S1x^2 + S1y^2)
//   sum_d2 = [2N S4x - 8 S3x S1x + 6 S2x^2] + [same for y]
//          + 2*[2N A22 - 4 A21 S1y - 4 A12 S1x + 2 S2x S2y + 4 A11^2]
// Identical reduction order in every block -> bit-identical threshold.
//
// Phase 2 — 64 rows in 4 groups of 16. Per 16-row group, three uniform
// paths: all-above-diagonal -> zero stores only; all-below -> no causal
// compare; straddle -> full check. Store volume per block is identical
// (256 KB) regardless of path -> perfect store balance at 2 blocks/CU.
// Row points hoisted per group (block-uniform scalar loads), row loop
// compile-time unrolled -> 16 independent compute+store streams.
//
// forward_bias via 0.5 + 0.5*dx*rsqrt(d2) == 0.5*(1+cos(atan2(dy,dx)));
// exactly 1.0 at the zero pair, matching atan2(0,1)=0.
// ---------------------------------------------------------------------------
#define PAB_ROWS 64    // rows per block tile
#define PAB_RG   16    // row group (unroll granularity)
#define PAB_TPB  256   // threads per block; tile width = PAB_TPB*4 columns

__global__ __launch_bounds__(PAB_TPB) void pab_fused_kernel(
        const float* __restrict__ r, float* __restrict__ out, int S) {
    const int b = blockIdx.z;
    const float2* emb = (const float2*)r + (size_t)b * S;
    const int tid = threadIdx.x;

    // ---------------- Phase 1: batch moments (every block) ----------------
    double s[12];
#pragma unroll
    for (int k = 0; k < 12; ++k) s[k] = 0.0;

    for (int idx0 = tid * 4; idx0 < S; idx0 += PAB_TPB * 4) {
        float4 c0 = *(const float4*)(emb + idx0);      // p0, p1
        float4 c1 = *(const float4*)(emb + idx0 + 2);  // p2, p3
        float xs[4] = {c0.x, c0.z, c1.x, c1.z};
        float ys[4] = {c0.y, c0.w, c1.y, c1.w};
#pragma unroll
        for (int k = 0; k < 4; ++k) {
            if (idx0 + k >= S) break;
            double x = (double)xs[k], y = (double)ys[k];
            double x2 = x * x, y2 = y * y;
            s[0]  += x;        s[1]  += y;
            s[2]  += x2;       s[3]  += y2;
            s[4]  += x2 * x;   s[5]  += y2 * y;
            s[6]  += x2 * x2;  s[7]  += y2 * y2;
            s[8]  += x * y;    s[9]  += x2 * y;
            s[10] += x * y2;   s[11] += x2 * y2;
        }
    }

    // Wave (64-lane) shuffle reduction — no barriers.
#pragma unroll
    for (int off = 32; off > 0; off >>= 1) {
#pragma unroll
        for (int k = 0; k < 12; ++k)
            s[k] += __shfl_down(s[k], off, 64);
    }

    __shared__ double part[PAB_TPB / 64][12];
    __shared__ double tot[12];
    __shared__ float thr_sh;
    const int wave = tid >> 6, lane = tid & 63;
    if (lane == 0) {
#pragma unroll
        for (int k = 0; k < 12; ++k) part[wave][k] = s[k];
    }
    __syncthreads();
    if (tid < 12) {
        double t = 0.0;
#pragma unroll
        for (int w = 0; w < PAB_TPB / 64; ++w) t += part[w][tid];
        tot[tid] = t;
    }
    __syncthreads();
    if (tid == 0) {
        double N = (double)S;
        double M = N * N;
        double S1x = tot[0], S1y = tot[1], S2x = tot[2], S2y = tot[3];
        double S3x = tot[4], S3y = tot[5], S4x = tot[6], S4y = tot[7];
        double A11 = tot[8], A21 = tot[9], A12 = tot[10], A22 = tot[11];

        double sum_d = 2.0 * N * (S2x + S2y) - 2.0 * (S1x * S1x + S1y * S1y);
        double qx = 2.0 * N * S4x - 8.0 * S3x * S1x + 6.0 * S2x * S2x;
        double qy = 2.0 * N * S4y - 8.0 * S3y * S1y + 6.0 * S2y * S2y;
        double cross = 2.0 * N * A22 - 4.0 * A21 * S1y - 4.0 * A12 * S1x
                     + 2.0 * S2x * S2y + 4.0 * A11 * A11;
        double sum_d2 = qx + qy + 2.0 * cross;

        double mean = sum_d / M;
        double var  = (sum_d2 - sum_d * sum_d / M) / (M - 1.0);  // ddof=1
        thr_sh = (float)(mean + 1.25 * sqrt(var));
    }
    __syncthreads();
    const float thr = thr_sh;

    // ---------------- Phase 2: write the 64 x 1024 tile ----------------
    const int i0 = blockIdx.y * PAB_ROWS;
    const int jt0 = blockIdx.x * PAB_TPB * 4;   // tile's first column
    const int j0 = jt0 + tid * 4;
    if (j0 >= S) return;

    const int jtile_last = min(jt0 + PAB_TPB * 4, S) - 1;
    const float4 z = {0.0f, 0.0f, 0.0f, 0.0f};

    // Column points for this thread (reused across all 64 rows).
    float4 c0 = *(const float4*)(emb + j0);
    float4 c1 = *(const float4*)(emb + j0 + 2);
    const float xs[4] = {c0.x, c0.z, c1.x, c1.z};
    const float ys[4] = {c0.y, c0.w, c1.y, c1.w};

    size_t orow = ((size_t)b * S + i0) * S + j0;

#pragma unroll
    for (int g = 0; g < PAB_ROWS / PAB_RG; ++g) {
        const int ig0 = i0 + g * PAB_RG;

        // (a) group entirely above the diagonal -> zeros only.
        if (jt0 > ig0 + PAB_RG - 1) {
#pragma unroll
            for (int rr = 0; rr < PAB_RG; ++rr) {
                if (ig0 + rr < S) *(float4*)(out + orow) = z;
                orow += S;
            }
            continue;
        }

        // Hoist the 16 block-uniform row points (scalar loads).
        float2 pis[PAB_RG];
#pragma unroll
        for (int rr = 0; rr < PAB_RG; ++rr)
            pis[rr] = emb[min(ig0 + rr, S - 1)];

        if (jtile_last <= ig0) {
            // (b) group entirely at/below the diagonal: no causal compare.
#pragma unroll
            for (int rr = 0; rr < PAB_RG; ++rr) {
                if (ig0 + rr < S) {
                    const float2 pi = pis[rr];
                    float4 res;
                    float* rp = &res.x;
#pragma unroll
                    for (int k = 0; k < 4; ++k) {
                        float dx = pi.x - xs[k];
                        float dy = pi.y - ys[k];
                        float d2 = fmaf(dx, dx, dy * dy);
                        float bias = (d2 > 0.0f)
                                   ? fmaf(0.5f * dx, rsqrtf(d2), 0.5f) : 1.0f;
                        rp[k] = (d2 <= thr) ? bias : 0.0f;
                    }
                    *(float4*)(out + orow) = res;
                }
                orow += S;
            }
        } else {
            // (c) straddling group: full per-element causal check.
#pragma unroll
            for (int rr = 0; rr < PAB_RG; ++rr) {
                const int i = ig0 + rr;
                if (i < S) {
                    const float2 pi = pis[rr];
                    float4 res;
                    float* rp = &res.x;
#pragma unroll
                    for (int k = 0; k < 4; ++k) {
                        float dx = pi.x - xs[k];
                        float dy = pi.y - ys[k];
                        float d2 = fmaf(dx, dx, dy * dy);
                        float bias = (d2 > 0.0f)
                                   ? fmaf(0.5f * dx, rsqrtf(d2), 0.5f) : 1.0f;
                        bool valid = (d2 <= thr) & ((j0 + k) <= i);
                        rp[k] = valid ? bias : 0.0f;
                    }
                    *(float4*)(out + orow) = res;
                }
                orow += S;
            }
        }
    }
}

extern "C" void kernel_launch(void* const* d_in, const int* in_sizes, int n_in,
                              void* d_out, int out_size, void* d_ws, size_t ws_size,
                              hipStream_t stream) {
    const float* r = (const float*)d_in[0];
    float* out = (float*)d_out;
    (void)d_ws; (void)ws_size;

    // in_sizes[0] = B*S*2, out_size = B*S*S  ->  S = 2*out_size / in_sizes[0]
    long in0 = in_sizes[0];
    int S = (int)((2L * (long)out_size) / in0);
    int B = (int)(in0 / (2L * S));

    dim3 block(PAB_TPB);
    dim3 grid((S + PAB_TPB * 4 - 1) / (PAB_TPB * 4),
              (S + PAB_ROWS - 1) / PAB_ROWS, B);
    pab_fused_kernel<<<grid, block, 0, stream>>>(r, out, S);
}

// Round 8
// 141.459 us; speedup vs baseline: 1.0475x; 1.0475x over previous
//
#include <hip/hip_runtime.h>
#include <math.h>

// ---------------------------------------------------------------------------
// Single fused kernel, 16-row x 1024-col tiles (2048 blocks = 8/CU; R7 showed
// fewer/bigger tiles regress: occupancy + zero/straddle load mixing matter).
//
// Block-uniform early path: tiles entirely above the diagonal (37.5% of
// blocks) store zeros and NEVER run phase-1 — they feed the store pipe from
// t=0 while compute tiles do their moments (phase-1 f64 VALU overlaps the
// store pipe across waves, per-CU mixing of block types).
//
// Phase 1 — remaining blocks redundantly recompute the batch's joint point
// moments in f64 (input 32 KB/batch, L2-broadcast). Closed-form
// mean/std(ddof=1) of the S*S pairwise dist_sq values:
//   sum_d  = 2N(S2x+S2y) - 2(S1x^2 + S1y^2)
//   sum_d2 = [2N S4x - 8 S3x S1x + 6 S2x^2] + [same for y]
//          + 2*[2N A22 - 4 A21 S1y - 4 A12 S1x + 2 S2x S2y + 4 A11^2]
// Identical reduction order in every block -> bit-identical threshold.
// f64 is REQUIRED: ~30 of 16.7M pairs sit within f32-threshold error of the
// boundary; a flipped mask bit costs absmax ~1.0 (tolerance is 2e-2).
//
// Phase 2 — 16 rows, hoisted block-uniform row points, compile-time
// unrolled row loop (16 independent compute+store streams). Paths (b)
// below-diagonal (no causal cmp) and (c) straddle (full check).
//
// forward_bias via 0.5 + 0.5*dx*rsqrt(d2) == 0.5*(1+cos(atan2(dy,dx)));
// exactly 1.0 at the zero pair, matching atan2(0,1)=0.
// ---------------------------------------------------------------------------
#define PAB_ROWS 16
#define PAB_TPB  256   // threads per block; tile width = PAB_TPB*4 columns

__global__ __launch_bounds__(PAB_TPB) void pab_fused_kernel(
        const float* __restrict__ r, float* __restrict__ out, int S) {
    const int b = blockIdx.z;
    const float2* emb = (const float2*)r + (size_t)b * S;
    const int tid = threadIdx.x;

    const int i0 = blockIdx.y * PAB_ROWS;
    const int jt0 = blockIdx.x * PAB_TPB * 4;   // tile's first column
    const int j0 = jt0 + tid * 4;

    // ---- Block-uniform zero path: skip phase-1 entirely, store at t=0 ----
    if (jt0 > i0 + PAB_ROWS - 1) {
        if (j0 >= S) return;
        size_t orow = ((size_t)b * S + i0) * S + j0;
        const float4 z = {0.0f, 0.0f, 0.0f, 0.0f};
#pragma unroll
        for (int rr = 0; rr < PAB_ROWS; ++rr) {
            if (i0 + rr < S) *(float4*)(out + orow) = z;
            orow += S;
        }
        return;
    }

    // ---------------- Phase 1: batch moments (compute blocks only) --------
    double s[12];
#pragma unroll
    for (int k = 0; k < 12; ++k) s[k] = 0.0;

    for (int idx0 = tid * 4; idx0 < S; idx0 += PAB_TPB * 4) {
        float4 c0 = *(const float4*)(emb + idx0);      // p0, p1
        float4 c1 = *(const float4*)(emb + idx0 + 2);  // p2, p3
        float xs[4] = {c0.x, c0.z, c1.x, c1.z};
        float ys[4] = {c0.y, c0.w, c1.y, c1.w};
#pragma unroll
        for (int k = 0; k < 4; ++k) {
            if (idx0 + k >= S) break;
            double x = (double)xs[k], y = (double)ys[k];
            double x2 = x * x, y2 = y * y;
            s[0]  += x;        s[1]  += y;
            s[2]  += x2;       s[3]  += y2;
            s[4]  += x2 * x;   s[5]  += y2 * y;
            s[6]  += x2 * x2;  s[7]  += y2 * y2;
            s[8]  += x * y;    s[9]  += x2 * y;
            s[10] += x * y2;   s[11] += x2 * y2;
        }
    }

    // Wave (64-lane) shuffle reduction — no barriers.
#pragma unroll
    for (int off = 32; off > 0; off >>= 1) {
#pragma unroll
        for (int k = 0; k < 12; ++k)
            s[k] += __shfl_down(s[k], off, 64);
    }

    __shared__ double part[PAB_TPB / 64][12];
    __shared__ double tot[12];
    __shared__ float thr_sh;
    const int wave = tid >> 6, lane = tid & 63;
    if (lane == 0) {
#pragma unroll
        for (int k = 0; k < 12; ++k) part[wave][k] = s[k];
    }
    __syncthreads();
    if (tid < 12) {
        double t = 0.0;
#pragma unroll
        for (int w = 0; w < PAB_TPB / 64; ++w) t += part[w][tid];
        tot[tid] = t;
    }
    __syncthreads();
    if (tid == 0) {
        double N = (double)S;
        double M = N * N;
        double S1x = tot[0], S1y = tot[1], S2x = tot[2], S2y = tot[3];
        double S3x = tot[4], S3y = tot[5], S4x = tot[6], S4y = tot[7];
        double A11 = tot[8], A21 = tot[9], A12 = tot[10], A22 = tot[11];

        double sum_d = 2.0 * N * (S2x + S2y) - 2.0 * (S1x * S1x + S1y * S1y);
        double qx = 2.0 * N * S4x - 8.0 * S3x * S1x + 6.0 * S2x * S2x;
        double qy = 2.0 * N * S4y - 8.0 * S3y * S1y + 6.0 * S2y * S2y;
        double cross = 2.0 * N * A22 - 4.0 * A21 * S1y - 4.0 * A12 * S1x
                     + 2.0 * S2x * S2y + 4.0 * A11 * A11;
        double sum_d2 = qx + qy + 2.0 * cross;

        double mean = sum_d / M;
        double var  = (sum_d2 - sum_d * sum_d / M) / (M - 1.0);  // ddof=1
        thr_sh = (float)(mean + 1.25 * sqrt(var));
    }
    __syncthreads();
    const float thr = thr_sh;

    // ---------------- Phase 2: write the 16 x 1024 tile ----------------
    if (j0 >= S) return;

    size_t orow = ((size_t)b * S + i0) * S + j0;

    // Hoist the 16 block-uniform row points (scalar loads, issued together).
    float2 pis[PAB_ROWS];
#pragma unroll
    for (int rr = 0; rr < PAB_ROWS; ++rr)
        pis[rr] = emb[min(i0 + rr, S - 1)];

    float4 c0 = *(const float4*)(emb + j0);
    float4 c1 = *(const float4*)(emb + j0 + 2);
    const float xs[4] = {c0.x, c0.z, c1.x, c1.z};
    const float ys[4] = {c0.y, c0.w, c1.y, c1.w};
    const int jtile_last = min(jt0 + PAB_TPB * 4, S) - 1;

    if (jtile_last <= i0) {
        // (b) tile entirely at/below the diagonal: no causal compare.
#pragma unroll
        for (int rr = 0; rr < PAB_ROWS; ++rr) {
            if (i0 + rr < S) {
                const float2 pi = pis[rr];
                float4 res;
                float* rp = &res.x;
#pragma unroll
                for (int k = 0; k < 4; ++k) {
                    float dx = pi.x - xs[k];
                    float dy = pi.y - ys[k];
                    float d2 = fmaf(dx, dx, dy * dy);
                    float bias = (d2 > 0.0f)
                               ? fmaf(0.5f * dx, rsqrtf(d2), 0.5f) : 1.0f;
                    rp[k] = (d2 <= thr) ? bias : 0.0f;
                }
                *(float4*)(out + orow) = res;
            }
            orow += S;
        }
    } else {
        // (c) straddling tile: full per-element causal check.
#pragma unroll
        for (int rr = 0; rr < PAB_ROWS; ++rr) {
            const int i = i0 + rr;
            if (i < S) {
                const float2 pi = pis[rr];
                float4 res;
                float* rp = &res.x;
#pragma unroll
                for (int k = 0; k < 4; ++k) {
                    float dx = pi.x - xs[k];
                    float dy = pi.y - ys[k];
                    float d2 = fmaf(dx, dx, dy * dy);
                    float bias = (d2 > 0.0f)
                               ? fmaf(0.5f * dx, rsqrtf(d2), 0.5f) : 1.0f;
                    bool valid = (d2 <= thr) & ((j0 + k) <= i);
                    rp[k] = valid ? bias : 0.0f;
                }
                *(float4*)(out + orow) = res;
            }
            orow += S;
        }
    }
}

extern "C" void kernel_launch(void* const* d_in, const int* in_sizes, int n_in,
                              void* d_out, int out_size, void* d_ws, size_t ws_size,
                              hipStream_t stream) {
    const float* r = (const float*)d_in[0];
    float* out = (float*)d_out;
    (void)d_ws; (void)ws_size;

    // in_sizes[0] = B*S*2, out_size = B*S*S  ->  S = 2*out_size / in_sizes[0]
    long in0 = in_sizes[0];
    int S = (int)((2L * (long)out_size) / in0);
    int B = (int)(in0 / (2L * S));

    dim3 block(PAB_TPB);
    dim3 grid((S + PAB_TPB * 4 - 1) / (PAB_TPB * 4),
              (S + PAB_ROWS - 1) / PAB_ROWS, B);
    pab_fused_kernel<<<grid, block, 0, stream>>>(r, out, S);
}